// Round 8
// baseline (1206.197 us; speedup 1.0000x reference)
//
#include <hip/hip_runtime.h>
#include <math.h>

// Problem constants
#define N_B 32
#define L_S 4096
#define D_M 768
#define H_N 12
#define NCH 32          // l-chunks (128 rows each)
#define XP  776         // padded LDS row pitch (768+8)

// ws layout (float offsets). NO zero-init required: every buffer is fully
// written before it is read (all split-k via plain partials, no atomics).
#define WS_QHP    0         // [16][768] qh split-k partials
#define WS_QK     12288     // [12][768] h-major
#define WS_QB     21504     // [12] (pad 64)
#define WS_MLC    21568     // [32*12][32] per-(n,h,lc) running max
#define WS_SLC    33856     // [32*12][32] per-(n,h,lc) running sum
#define WS_XBP    46144     // [32 lc][12 h][32 n][768 d] unnormalized partials
#define WS_OP     9483328   // [8 kk][32][768] o partials
#define WS_XAP    9679936   // [8 kk][32][768] xa partials
#define WS_XAS    9876544   // [32][768] summed xa (written by ln)
#define WS_Y      9901120   // [32][768]
#define WS_H1P    9925696   // [16 kk][3072 j][32 n] mlp1 partials (j-major!)
#define WS_MACCP  11498560  // [64 kk][32][768] mlp2 partials

// ---------------------------------------------------------------------------
// qh partials: qhp[ky][i] = 0.125*(probe[d0:d0+48] @ wq)[i] (+0.125*bq at ky0).
__global__ __launch_bounds__(256) void qh_kernel(
    const float* __restrict__ probe, const float* __restrict__ wq,
    const float* __restrict__ bq, float* __restrict__ qhp) {
    int i = blockIdx.x * 256 + threadIdx.x;
    int ky = blockIdx.y, d0 = ky * 48;
    float acc = 0.f;
    for (int dd = 0; dd < 48; ++dd)
        acc += probe[d0 + dd] * wq[(size_t)(d0 + dd) * 768 + i];
    acc *= 0.125f;
    if (ky == 0) acc += 0.125f * bq[i];
    qhp[ky * 768 + i] = acc;
}

// qk[h][d] = sum_e qh[h*64+e]*wk[d*768+h*64+e]; qb[h] = qh_h . bk_h.
__global__ __launch_bounds__(256) void qk_kernel(
    const float* __restrict__ qhp, const float* __restrict__ wk,
    const float* __restrict__ bk, float* __restrict__ qk,
    float* __restrict__ qb) {
    int h = blockIdx.x, dt = blockIdx.y, t = threadIdx.x;
    __shared__ float qh_s[64];
    if (t < 64) {
        float s = 0.f;
        #pragma unroll
        for (int k = 0; k < 16; ++k) s += qhp[k * 768 + h * 64 + t];
        qh_s[t] = s;
    }
    __syncthreads();
    int d = dt * 256 + t;
    const float4* wk4 = (const float4*)(wk + (size_t)d * 768 + h * 64);
    const float4* qh4 = (const float4*)qh_s;
    float acc = 0.f;
    #pragma unroll
    for (int e4 = 0; e4 < 16; ++e4) {
        float4 w = wk4[e4], q = qh4[e4];
        acc += w.x * q.x + w.y * q.y + w.z * q.z + w.w * q.w;
    }
    qk[h * 768 + d] = acc;
    if (dt == 0 && t < 64) {
        float v = qh_s[t] * bk[h * 64 + t];
        #pragma unroll
        for (int off = 32; off > 0; off >>= 1) v += __shfl_xor(v, off);
        if (t == 0) qb[h] = v;
    }
}

// ---------------------------------------------------------------------------
// Fused flash-style attention. R8 changes vs R7 (which measured 429us at
// 23% occupancy, VALUBusy 16% -> barrier/latency-serialized):
//  * NCH 32 -> 1024 blocks = 4 blocks/CU (launch_bounds(256,4), VGPR<=128).
//  * 2 barriers/iter instead of 3: softmax bookkeeping is per-wave-redundant.
//    After the lg_s barrier each compute wave's lanes 0-11 update PRIVATE
//    (m,s) register state and write a per-wave w_s/sc_s slice; phase2 reads
//    only its own wave's slice (in-wave LDS ordering, no barrier needed).
// Output: xbp[lc][h][n][768] partials + per-chunk (m,s); exact merge via
// softmax linearity in oproj.
__global__ __launch_bounds__(256, 4) void attn_fused(
    const float* __restrict__ x, const float* __restrict__ qk,
    const float* __restrict__ qb, float* __restrict__ xbp,
    float* __restrict__ mlc, float* __restrict__ slc) {
    __shared__ __align__(16) float xs[2 * 4 * XP];  // 24.8 KB
    __shared__ __align__(16) float lg_s[64];
    __shared__ __align__(16) float w_s[3 * 64];     // per-wave tile weights
    __shared__ __align__(16) float sc_s[3 * 16];    // per-wave rescale
    __shared__ __align__(16) float qb_s[16];
    int lc = blockIdx.x, n = blockIdx.y, t = threadIdx.x;
    int lane = t & 63, w = t >> 6;
    size_t xbase = ((size_t)n * 4096 + lc * 128) * 768;

    int h1 = t >> 4, q1 = t & 15;          // phase1 map (valid t<192)
    float4 qk_r[12];
    if (t < 192) {
        const float4* qk4 = (const float4*)qk;
        #pragma unroll
        for (int k = 0; k < 12; ++k)
            qk_r[k] = qk4[h1 * 192 + k * 16 + q1];   // cols q1*4+64k..+3
    }
    if (t < 12) qb_s[t] = qb[t];
    float ms = -1e30f, ss = 0.f;           // per-wave state (lanes 0-11, w<3)
    // stage subtile 0 into buffer 0 (all threads)
    {
        const float4* s0 = (const float4*)(x + xbase);
        for (int j = t; j < 768; j += 256)
            *(float4*)&xs[(j / 192) * XP + (j % 192) * 4] = s0[j];
    }
    float4 acc4[12];
    #pragma unroll
    for (int h = 0; h < 12; ++h) acc4[h] = make_float4(0.f, 0.f, 0.f, 0.f);
    __syncthreads();

    int p = 0;
    for (int it = 0; it < 32; ++it) {
        // wave 3: stage subtile it+1 into buffer p^1
        if (w == 3 && it + 1 < 32) {
            const float4* src = (const float4*)(x + xbase + (size_t)(it + 1) * 3072);
            #pragma unroll
            for (int j = 0; j < 12; ++j) {
                int f = lane + 64 * j;
                float4 v = src[f];
                *(float4*)&xs[(p ^ 1) * 4 * XP + (f / 192) * XP + (f % 192) * 4] = v;
            }
        }
        // phase1: 48 dots (4r x 12h), qk from registers, x from LDS
        if (t < 192) {
            const float* xbb = &xs[p * 4 * XP];
            float a[4];
            #pragma unroll
            for (int r = 0; r < 4; ++r) {
                const float4* xr = (const float4*)&xbb[r * XP + q1 * 4];
                float s = 0.f;
                #pragma unroll
                for (int k = 0; k < 12; ++k) {
                    float4 xv = xr[k * 16];
                    float4 kv = qk_r[k];
                    s += xv.x * kv.x + xv.y * kv.y + xv.z * kv.z + xv.w * kv.w;
                }
                a[r] = s;
            }
            #pragma unroll
            for (int r = 0; r < 4; ++r) {
                a[r] += __shfl_xor(a[r], 1);
                a[r] += __shfl_xor(a[r], 2);
                a[r] += __shfl_xor(a[r], 4);
                a[r] += __shfl_xor(a[r], 8);
            }
            if (q1 == 0) {
                #pragma unroll
                for (int r = 0; r < 4; ++r) lg_s[r * 16 + h1] = a[r] + qb_s[h1];
            }
        }
        __syncthreads();   // B1: lg_s complete; staged p^1 complete
        // bookkeeping: EACH compute wave's lanes 0-11 redundantly update
        // private (ms,ss) and write this wave's w_s/sc_s slice.
        if (t < 192 && lane < 12) {
            float l0 = lg_s[0 * 16 + lane], l1 = lg_s[1 * 16 + lane];
            float l2 = lg_s[2 * 16 + lane], l3 = lg_s[3 * 16 + lane];
            float mt = fmaxf(fmaxf(l0, l1), fmaxf(l2, l3));
            float mn = fmaxf(ms, mt);
            float sc = __expf(ms - mn);
            float e0 = __expf(l0 - mn), e1 = __expf(l1 - mn);
            float e2 = __expf(l2 - mn), e3 = __expf(l3 - mn);
            w_s[w * 64 + 0 * 16 + lane] = e0; w_s[w * 64 + 1 * 16 + lane] = e1;
            w_s[w * 64 + 2 * 16 + lane] = e2; w_s[w * 64 + 3 * 16 + lane] = e3;
            sc_s[w * 16 + lane] = sc;
            ms = mn;
            ss = ss * sc + (e0 + e1 + e2 + e3);
        }
        // phase2: t<192 owns 4 contiguous d-cols; reads OWN wave's w_s/sc_s
        // (in-wave write->read ordering via lgkmcnt, no barrier).
        if (t < 192) {
            const float* xb = &xs[p * 4 * XP];
            const float4* w4 = (const float4*)&w_s[w * 64];
            const float4* sc4 = (const float4*)&sc_s[w * 16];
            float4 sa = sc4[0], sb = sc4[1], sc = sc4[2];
            acc4[0].x *= sa.x; acc4[0].y *= sa.x; acc4[0].z *= sa.x; acc4[0].w *= sa.x;
            acc4[1].x *= sa.y; acc4[1].y *= sa.y; acc4[1].z *= sa.y; acc4[1].w *= sa.y;
            acc4[2].x *= sa.z; acc4[2].y *= sa.z; acc4[2].z *= sa.z; acc4[2].w *= sa.z;
            acc4[3].x *= sa.w; acc4[3].y *= sa.w; acc4[3].z *= sa.w; acc4[3].w *= sa.w;
            acc4[4].x *= sb.x; acc4[4].y *= sb.x; acc4[4].z *= sb.x; acc4[4].w *= sb.x;
            acc4[5].x *= sb.y; acc4[5].y *= sb.y; acc4[5].z *= sb.y; acc4[5].w *= sb.y;
            acc4[6].x *= sb.z; acc4[6].y *= sb.z; acc4[6].z *= sb.z; acc4[6].w *= sb.z;
            acc4[7].x *= sb.w; acc4[7].y *= sb.w; acc4[7].z *= sb.w; acc4[7].w *= sb.w;
            acc4[8].x *= sc.x; acc4[8].y *= sc.x; acc4[8].z *= sc.x; acc4[8].w *= sc.x;
            acc4[9].x *= sc.y; acc4[9].y *= sc.y; acc4[9].z *= sc.y; acc4[9].w *= sc.y;
            acc4[10].x *= sc.z; acc4[10].y *= sc.z; acc4[10].z *= sc.z; acc4[10].w *= sc.z;
            acc4[11].x *= sc.w; acc4[11].y *= sc.w; acc4[11].z *= sc.w; acc4[11].w *= sc.w;
            #pragma unroll
            for (int l = 0; l < 4; ++l) {
                float4 xv = *(const float4*)&xb[l * XP + 4 * t];
                float4 wa = w4[l * 4], wb = w4[l * 4 + 1], wc = w4[l * 4 + 2];
                acc4[0].x += wa.x * xv.x; acc4[0].y += wa.x * xv.y; acc4[0].z += wa.x * xv.z; acc4[0].w += wa.x * xv.w;
                acc4[1].x += wa.y * xv.x; acc4[1].y += wa.y * xv.y; acc4[1].z += wa.y * xv.z; acc4[1].w += wa.y * xv.w;
                acc4[2].x += wa.z * xv.x; acc4[2].y += wa.z * xv.y; acc4[2].z += wa.z * xv.z; acc4[2].w += wa.z * xv.w;
                acc4[3].x += wa.w * xv.x; acc4[3].y += wa.w * xv.y; acc4[3].z += wa.w * xv.z; acc4[3].w += wa.w * xv.w;
                acc4[4].x += wb.x * xv.x; acc4[4].y += wb.x * xv.y; acc4[4].z += wb.x * xv.z; acc4[4].w += wb.x * xv.w;
                acc4[5].x += wb.y * xv.x; acc4[5].y += wb.y * xv.y; acc4[5].z += wb.y * xv.z; acc4[5].w += wb.y * xv.w;
                acc4[6].x += wb.z * xv.x; acc4[6].y += wb.z * xv.y; acc4[6].z += wb.z * xv.z; acc4[6].w += wb.z * xv.w;
                acc4[7].x += wb.w * xv.x; acc4[7].y += wb.w * xv.y; acc4[7].z += wb.w * xv.z; acc4[7].w += wb.w * xv.w;
                acc4[8].x += wc.x * xv.x; acc4[8].y += wc.x * xv.y; acc4[8].z += wc.x * xv.z; acc4[8].w += wc.x * xv.w;
                acc4[9].x += wc.y * xv.x; acc4[9].y += wc.y * xv.y; acc4[9].z += wc.y * xv.z; acc4[9].w += wc.y * xv.w;
                acc4[10].x += wc.z * xv.x; acc4[10].y += wc.z * xv.y; acc4[10].z += wc.z * xv.z; acc4[10].w += wc.z * xv.w;
                acc4[11].x += wc.w * xv.x; acc4[11].y += wc.w * xv.y; acc4[11].z += wc.w * xv.z; acc4[11].w += wc.w * xv.w;
            }
        }
        __syncthreads();   // B2: reads of buf p done; next iter may overwrite
        p ^= 1;
    }
    // write partials + per-chunk stats. xbp layout [lc][h][n][d].
    if (t < 192) {
        #pragma unroll
        for (int h = 0; h < 12; ++h)
            *(float4*)&xbp[(((size_t)lc * 12 + h) * 32 + n) * 768 + 4 * t] = acc4[h];
    }
    if (w == 0 && lane < 12) {
        mlc[((size_t)n * 12 + lane) * 32 + lc] = ms;
        slc[((size_t)n * 12 + lane) * 32 + lc] = ss;
    }
}

// ---------------------------------------------------------------------------
// o partials: op[kk][n][h*64+e] = sum_{d in kk} xbar[n,h,d]*wv[d,h,e] (+bv@kk0).
// Grid (12 h, 8 kk). Softmax merge from (mlc,slc); xbar reconstructed by
// scale-summing the 32 chunk partials. Gather is d-fastest -> coalesced
// (xbp layout [lc][h][n][d]); xb_s pitch 36 avoids write bank conflicts.
__global__ __launch_bounds__(256) void oproj_kernel(
    const float* __restrict__ xbp, const float* __restrict__ mlc,
    const float* __restrict__ slc, const float* __restrict__ wv,
    const float* __restrict__ bv, float* __restrict__ op) {
    int h = blockIdx.x, kk = blockIdx.y, t = threadIdx.x;
    int d0 = kk * 96;
    __shared__ __align__(16) float wv_s[96 * 64];
    __shared__ __align__(16) float xb_s[96 * 36];
    __shared__ float scl_s[32 * 32];   // [lc][nn]
    if (t < 32) {
        float M = -1e30f;
        #pragma unroll
        for (int c = 0; c < 32; ++c) M = fmaxf(M, mlc[((size_t)t * 12 + h) * 32 + c]);
        float e[32], T = 0.f;
        #pragma unroll
        for (int c = 0; c < 32; ++c) {
            e[c] = __expf(mlc[((size_t)t * 12 + h) * 32 + c] - M);
            T += slc[((size_t)t * 12 + h) * 32 + c] * e[c];
        }
        float inv = 1.f / T;
        #pragma unroll
        for (int c = 0; c < 32; ++c) scl_s[c * 32 + t] = e[c] * inv;
    }
    for (int i = t; i < 96 * 64; i += 256) {
        int d = i >> 6, e = i & 63;
        wv_s[i] = wv[(size_t)(d0 + d) * 768 + h * 64 + e];
    }
    __syncthreads();
    for (int idx = t; idx < 96 * 32; idx += 256) {
        int d = idx % 96, nn = idx / 96;   // consecutive lanes -> consecutive d
        float s = 0.f;
        #pragma unroll
        for (int lcc = 0; lcc < 32; ++lcc)
            s += xbp[(((size_t)lcc * 12 + h) * 32 + nn) * 768 + d0 + d]
               * scl_s[lcc * 32 + nn];
        xb_s[d * 36 + nn] = s;
    }
    __syncthreads();
    int e = t & 63, ng = t >> 6;
    float acc[8] = {0, 0, 0, 0, 0, 0, 0, 0};
    for (int d = 0; d < 96; ++d) {
        float wvv = wv_s[d * 64 + e];
        const float4* xb4 = (const float4*)&xb_s[d * 36 + ng * 8];
        float4 p0 = xb4[0], p1 = xb4[1];
        acc[0] += p0.x * wvv; acc[1] += p0.y * wvv; acc[2] += p0.z * wvv; acc[3] += p0.w * wvv;
        acc[4] += p1.x * wvv; acc[5] += p1.y * wvv; acc[6] += p1.z * wvv; acc[7] += p1.w * wvv;
    }
    float bvv = (kk == 0) ? bv[h * 64 + e] : 0.f;
    #pragma unroll
    for (int k = 0; k < 8; ++k)
        op[(size_t)kk * 24576 + (size_t)(ng * 8 + k) * 768 + h * 64 + e] = acc[k] + bvv;
}

// xa partials: xap[kk][n][d] = sum_{i in kk} o[n][i]*wo[i*768+d] (+bo@kk0).
// Grid (3 dtile, 8 kk). o summed from its 8 partials; gather i-fastest
// (coalesced), o_s pitch 36.
__global__ __launch_bounds__(256) void xaproj_kernel(
    const float* __restrict__ op, const float* __restrict__ wo,
    const float* __restrict__ bo, float* __restrict__ xap) {
    int dt = blockIdx.x, kk = blockIdx.y, t = threadIdx.x;
    int i0 = kk * 96;
    __shared__ __align__(16) float o_s[96 * 36];
    for (int idx = t; idx < 96 * 32; idx += 256) {
        int i = idx % 96, nn = idx / 96;   // consecutive lanes -> consecutive i
        float s = 0.f;
        #pragma unroll
        for (int pp = 0; pp < 8; ++pp)
            s += op[(size_t)pp * 24576 + (size_t)nn * 768 + i0 + i];
        o_s[i * 36 + nn] = s;
    }
    __syncthreads();
    int d = dt * 256 + t;
    float acc[32];
    #pragma unroll
    for (int nn = 0; nn < 32; ++nn) acc[nn] = 0.f;
    for (int i = 0; i < 96; ++i) {
        float w = wo[(size_t)(i0 + i) * 768 + d];
        const float4* o4 = (const float4*)&o_s[i * 36];
        #pragma unroll
        for (int qq = 0; qq < 8; ++qq) {
            float4 f = o4[qq];
            acc[qq * 4 + 0] += f.x * w; acc[qq * 4 + 1] += f.y * w;
            acc[qq * 4 + 2] += f.z * w; acc[qq * 4 + 3] += f.w * w;
        }
    }
    float bov = (kk == 0) ? bo[d] : 0.f;
    #pragma unroll
    for (int nn = 0; nn < 32; ++nn)
        xap[(size_t)kk * 24576 + (size_t)nn * 768 + d] = acc[nn] + bov;
}

// ---------------------------------------------------------------------------
// xa = sum of 8 partials (stored to xas for the residual); y = LayerNorm(xa).
__global__ __launch_bounds__(256) void ln_kernel(
    const float* __restrict__ xap, const float* __restrict__ ln_scale,
    const float* __restrict__ ln_bias, float* __restrict__ xas,
    float* __restrict__ y) {
    int n = blockIdx.x, tid = threadIdx.x;
    __shared__ float xs[768];
    __shared__ float red[4];
    for (int i = tid; i < 768; i += 256) {
        float s = 0.f;
        #pragma unroll
        for (int pp = 0; pp < 8; ++pp)
            s += xap[(size_t)pp * 24576 + (size_t)n * 768 + i];
        xs[i] = s;
        xas[(size_t)n * 768 + i] = s;
    }
    __syncthreads();
    float lsum = 0.f;
    for (int i = tid; i < 768; i += 256) lsum += xs[i];
    #pragma unroll
    for (int off = 32; off > 0; off >>= 1) lsum += __shfl_xor(lsum, off);
    int wave = tid >> 6;
    if ((tid & 63) == 0) red[wave] = lsum;
    __syncthreads();
    float mu = (red[0] + red[1] + red[2] + red[3]) * (1.f / 768.f);
    __syncthreads();
    float lsq = 0.f;
    for (int i = tid; i < 768; i += 256) { float c = xs[i] - mu; lsq += c * c; }
    #pragma unroll
    for (int off = 32; off > 0; off >>= 1) lsq += __shfl_xor(lsq, off);
    if ((tid & 63) == 0) red[wave] = lsq;
    __syncthreads();
    float var = (red[0] + red[1] + red[2] + red[3]) * (1.f / 768.f);
    float rs = rsqrtf(var + 1e-6f);
    for (int i = tid; i < 768; i += 256)
        y[(size_t)n * 768 + i] = (xs[i] - mu) * rs * ln_scale[i] + ln_bias[i];
}

// ---------------------------------------------------------------------------
// h1 partials: h1p[kk][j][nn] (j-major) = sum_{d in kk(48)} y[n][d]*w1[d][j].
// Grid (12 jtile, 16 kk). Store is per-thread-contiguous (float4-able).
__global__ __launch_bounds__(256) void mlp1_kernel(
    const float* __restrict__ y, const float* __restrict__ w1,
    float* __restrict__ h1p) {
    int jt = blockIdx.x, kk = blockIdx.y, t = threadIdx.x;
    int d0 = kk * 48;
    __shared__ __align__(16) float y_s[48 * 32];
    for (int idx = t; idx < 48 * 32; idx += 256) {
        int d = idx >> 5, nn = idx & 31;
        y_s[idx] = y[(size_t)nn * 768 + d0 + d];
    }
    __syncthreads();
    int j = jt * 256 + t;
    float acc[32];
    #pragma unroll
    for (int nn = 0; nn < 32; ++nn) acc[nn] = 0.f;
    for (int d = 0; d < 48; ++d) {
        float w = w1[(size_t)(d0 + d) * 3072 + j];
        const float4* y4 = (const float4*)&y_s[d * 32];
        #pragma unroll
        for (int qq = 0; qq < 8; ++qq) {
            float4 f = y4[qq];
            acc[qq * 4 + 0] += f.x * w; acc[qq * 4 + 1] += f.y * w;
            acc[qq * 4 + 2] += f.z * w; acc[qq * 4 + 3] += f.w * w;
        }
    }
    float* dst = h1p + (size_t)kk * 98304 + (size_t)j * 32;
    #pragma unroll
    for (int qq = 0; qq < 8; ++qq)
        *(float4*)&dst[qq * 4] = make_float4(acc[qq * 4], acc[qq * 4 + 1],
                                             acc[qq * 4 + 2], acc[qq * 4 + 3]);
}

// macc partials: maccp[kk][n][d] = sum_{j in kk(48)} gelu(h1+b1)[n][j]*w2[j][d].
// Grid (3 dtile, 64 kk). h1 gather is linear in idx (h1p j-major) -> coalesced.
__global__ __launch_bounds__(256) void mlp2_kernel(
    const float* __restrict__ h1p, const float* __restrict__ b1,
    const float* __restrict__ w2, float* __restrict__ maccp) {
    int dt = blockIdx.x, kk = blockIdx.y, t = threadIdx.x;
    int j0 = kk * 48;
    __shared__ __align__(16) float h_s[48 * 32];
    for (int idx = t; idx < 48 * 32; idx += 256) {
        int j = idx >> 5;
        float tv = b1[j0 + j];
        #pragma unroll
        for (int pp = 0; pp < 16; ++pp)
            tv += h1p[(size_t)pp * 98304 + (size_t)j0 * 32 + idx];
        float u = 0.7978845608028654f * (tv + 0.044715f * tv * tv * tv);
        h_s[idx] = 0.5f * tv * (1.f + tanhf(u));
    }
    __syncthreads();
    int d = dt * 256 + t;
    float acc[32];
    #pragma unroll
    for (int nn = 0; nn < 32; ++nn) acc[nn] = 0.f;
    for (int j = 0; j < 48; ++j) {
        float w = w2[(size_t)(j0 + j) * 768 + d];
        const float4* h4 = (const float4*)&h_s[j * 32];
        #pragma unroll
        for (int qq = 0; qq < 8; ++qq) {
            float4 f = h4[qq];
            acc[qq * 4 + 0] += f.x * w; acc[qq * 4 + 1] += f.y * w;
            acc[qq * 4 + 2] += f.z * w; acc[qq * 4 + 3] += f.w * w;
        }
    }
    #pragma unroll
    for (int nn = 0; nn < 32; ++nn)
        maccp[(size_t)kk * 24576 + (size_t)nn * 768 + d] = acc[nn];
}

// out = xas + b2 + sum_64 maccp. Grid 32 n.
__global__ __launch_bounds__(256) void final_kernel(
    const float* __restrict__ xas, const float* __restrict__ b2,
    const float* __restrict__ maccp, float* __restrict__ out) {
    int n = blockIdx.x, t = threadIdx.x;
    for (int i = t; i < 768; i += 256) {
        float s = xas[(size_t)n * 768 + i] + b2[i];
        #pragma unroll
        for (int k = 0; k < 64; ++k)
            s += maccp[(size_t)k * 24576 + (size_t)n * 768 + i];
        out[(size_t)n * 768 + i] = s;
    }
}

// ---------------------------------------------------------------------------
extern "C" void kernel_launch(void* const* d_in, const int* in_sizes, int n_in,
                              void* d_out, int out_size, void* d_ws, size_t ws_size,
                              hipStream_t stream) {
    const float* x        = (const float*)d_in[0];
    const float* probe    = (const float*)d_in[1];
    const float* wq       = (const float*)d_in[2];
    const float* bq       = (const float*)d_in[3];
    const float* wk       = (const float*)d_in[4];
    const float* bk       = (const float*)d_in[5];
    const float* wv       = (const float*)d_in[6];
    const float* bv       = (const float*)d_in[7];
    const float* wo       = (const float*)d_in[8];
    const float* bo       = (const float*)d_in[9];
    const float* ln_scale = (const float*)d_in[10];
    const float* ln_bias  = (const float*)d_in[11];
    const float* w1       = (const float*)d_in[12];
    const float* b1       = (const float*)d_in[13];
    const float* w2       = (const float*)d_in[14];
    const float* b2       = (const float*)d_in[15];
    float* out = (float*)d_out;
    float* ws  = (float*)d_ws;

    float* qhp   = ws + WS_QHP;
    float* qk    = ws + WS_QK;
    float* qb    = ws + WS_QB;
    float* mlc   = ws + WS_MLC;
    float* slc   = ws + WS_SLC;
    float* xbp   = ws + WS_XBP;
    float* op    = ws + WS_OP;
    float* xap   = ws + WS_XAP;
    float* xas   = ws + WS_XAS;
    float* y     = ws + WS_Y;
    float* h1p   = ws + WS_H1P;
    float* maccp = ws + WS_MACCP;

    qh_kernel<<<dim3(3, 16), 256, 0, stream>>>(probe, wq, bq, qhp);
    qk_kernel<<<dim3(12, 3), 256, 0, stream>>>(qhp, wk, bk, qk, qb);
    attn_fused<<<dim3(NCH, 32), 256, 0, stream>>>(x, qk, qb, xbp, mlc, slc);
    oproj_kernel<<<dim3(12, 8), 256, 0, stream>>>(xbp, mlc, slc, wv, bv, op);
    xaproj_kernel<<<dim3(3, 8), 256, 0, stream>>>(op, wo, bo, xap);
    ln_kernel<<<N_B, 256, 0, stream>>>(xap, ln_scale, ln_bias, xas, y);
    mlp1_kernel<<<dim3(12, 16), 256, 0, stream>>>(y, w1, h1p);
    mlp2_kernel<<<dim3(3, 64), 256, 0, stream>>>(h1p, b1, w2, maccp);
    final_kernel<<<N_B, 256, 0, stream>>>(xas, b2, maccp, out);
}

// Round 10
// 981.012 us; speedup vs baseline: 1.2295x; 1.2295x over previous
//
#include <hip/hip_runtime.h>
#include <math.h>

// Problem constants
#define N_B 32
#define L_S 4096
#define D_M 768
#define H_N 12
#define NCH 32          // l-chunks (128 rows each)
#define XP  776         // padded LDS row pitch (768+8)

// ws layout (float offsets). NO zero-init required: every buffer is fully
// written before it is read (all split-k via plain partials, no atomics).
#define WS_QHP    0         // [16][768] qh split-k partials
#define WS_QK     12288     // [12][768] h-major
#define WS_QB     21504     // [12] (pad 64)
#define WS_MLC    21568     // [32*12][32] per-(n,h,lc) running max
#define WS_SLC    33856     // [32*12][32] per-(n,h,lc) running sum
#define WS_XBP    46144     // [32 lc][12 h][32 n][768 d] unnormalized partials
#define WS_OP     9483328   // [8 kk][32][768] o partials
#define WS_XAP    9679936   // [8 kk][32][768] xa partials
#define WS_XAS    9876544   // [32][768] summed xa (written by ln)
#define WS_Y      9901120   // [32][768]
#define WS_H1P    9925696   // [16 kk][3072 j][32 n] mlp1 partials (j-major)
#define WS_MACCP  11498560  // [64 kk][32][768] mlp2 partials

// ---------------------------------------------------------------------------
// qh partials: qhp[ky][i] = 0.125*(probe[d0:d0+48] @ wq)[i] (+0.125*bq at ky0).
__global__ __launch_bounds__(256) void qh_kernel(
    const float* __restrict__ probe, const float* __restrict__ wq,
    const float* __restrict__ bq, float* __restrict__ qhp) {
    int i = blockIdx.x * 256 + threadIdx.x;
    int ky = blockIdx.y, d0 = ky * 48;
    float acc = 0.f;
    for (int dd = 0; dd < 48; ++dd)
        acc += probe[d0 + dd] * wq[(size_t)(d0 + dd) * 768 + i];
    acc *= 0.125f;
    if (ky == 0) acc += 0.125f * bq[i];
    qhp[ky * 768 + i] = acc;
}

// qk[h][d] = sum_e qh[h*64+e]*wk[d*768+h*64+e]; qb[h] = qh_h . bk_h.
__global__ __launch_bounds__(256) void qk_kernel(
    const float* __restrict__ qhp, const float* __restrict__ wk,
    const float* __restrict__ bk, float* __restrict__ qk,
    float* __restrict__ qb) {
    int h = blockIdx.x, dt = blockIdx.y, t = threadIdx.x;
    __shared__ float qh_s[64];
    if (t < 64) {
        float s = 0.f;
        #pragma unroll
        for (int k = 0; k < 16; ++k) s += qhp[k * 768 + h * 64 + t];
        qh_s[t] = s;
    }
    __syncthreads();
    int d = dt * 256 + t;
    const float4* wk4 = (const float4*)(wk + (size_t)d * 768 + h * 64);
    const float4* qh4 = (const float4*)qh_s;
    float acc = 0.f;
    #pragma unroll
    for (int e4 = 0; e4 < 16; ++e4) {
        float4 w = wk4[e4], q = qh4[e4];
        acc += w.x * q.x + w.y * q.y + w.z * q.z + w.w * q.w;
    }
    qk[h * 768 + d] = acc;
    if (dt == 0 && t < 64) {
        float v = qh_s[t] * bk[h * 64 + t];
        #pragma unroll
        for (int off = 32; off > 0; off >>= 1) v += __shfl_xor(v, off);
        if (t == 0) qb[h] = v;
    }
}

// ---------------------------------------------------------------------------
// Fused flash-style attention. R9: R8's 1024-block grid + 2-barrier structure
// with R7's no-spill codegen: __launch_bounds__(256,2). R8's (256,4) squeezed
// VGPR to 64 < ~108 live state -> qk_r/acc4 spilled to scratch (measured:
// WRITE_SIZE 19->804 MB, dur 429->622us). At 108 VGPR the HW already allows
// 4 waves/SIMD, so the 1024-block grid alone gives 4 blocks/CU.
__global__ __launch_bounds__(256, 2) void attn_fused(
    const float* __restrict__ x, const float* __restrict__ qk,
    const float* __restrict__ qb, float* __restrict__ xbp,
    float* __restrict__ mlc, float* __restrict__ slc) {
    __shared__ __align__(16) float xs[2 * 4 * XP];  // 24.8 KB
    __shared__ __align__(16) float lg_s[64];
    __shared__ __align__(16) float w_s[3 * 64];     // per-wave tile weights
    __shared__ __align__(16) float sc_s[3 * 16];    // per-wave rescale
    __shared__ __align__(16) float qb_s[16];
    int lc = blockIdx.x, n = blockIdx.y, t = threadIdx.x;
    int lane = t & 63, w = t >> 6;
    size_t xbase = ((size_t)n * 4096 + lc * 128) * 768;

    int h1 = t >> 4, q1 = t & 15;          // phase1 map (valid t<192)
    float4 qk_r[12];
    if (t < 192) {
        const float4* qk4 = (const float4*)qk;
        #pragma unroll
        for (int k = 0; k < 12; ++k)
            qk_r[k] = qk4[h1 * 192 + k * 16 + q1];   // cols q1*4+64k..+3
    }
    if (t < 12) qb_s[t] = qb[t];
    float ms = -1e30f, ss = 0.f;           // per-wave state (lanes 0-11, w<3)
    // stage subtile 0 into buffer 0 (all threads)
    {
        const float4* s0 = (const float4*)(x + xbase);
        for (int j = t; j < 768; j += 256)
            *(float4*)&xs[(j / 192) * XP + (j % 192) * 4] = s0[j];
    }
    float4 acc4[12];
    #pragma unroll
    for (int h = 0; h < 12; ++h) acc4[h] = make_float4(0.f, 0.f, 0.f, 0.f);
    __syncthreads();

    int p = 0;
    for (int it = 0; it < 32; ++it) {
        // wave 3: stage subtile it+1 into buffer p^1
        if (w == 3 && it + 1 < 32) {
            const float4* src = (const float4*)(x + xbase + (size_t)(it + 1) * 3072);
            #pragma unroll
            for (int j = 0; j < 12; ++j) {
                int f = lane + 64 * j;
                float4 v = src[f];
                *(float4*)&xs[(p ^ 1) * 4 * XP + (f / 192) * XP + (f % 192) * 4] = v;
            }
        }
        // phase1: 48 dots (4r x 12h), qk from registers, x from LDS
        if (t < 192) {
            const float* xbb = &xs[p * 4 * XP];
            float a[4];
            #pragma unroll
            for (int r = 0; r < 4; ++r) {
                const float4* xr = (const float4*)&xbb[r * XP + q1 * 4];
                float s = 0.f;
                #pragma unroll
                for (int k = 0; k < 12; ++k) {
                    float4 xv = xr[k * 16];
                    float4 kv = qk_r[k];
                    s += xv.x * kv.x + xv.y * kv.y + xv.z * kv.z + xv.w * kv.w;
                }
                a[r] = s;
            }
            #pragma unroll
            for (int r = 0; r < 4; ++r) {
                a[r] += __shfl_xor(a[r], 1);
                a[r] += __shfl_xor(a[r], 2);
                a[r] += __shfl_xor(a[r], 4);
                a[r] += __shfl_xor(a[r], 8);
            }
            if (q1 == 0) {
                #pragma unroll
                for (int r = 0; r < 4; ++r) lg_s[r * 16 + h1] = a[r] + qb_s[h1];
            }
        }
        __syncthreads();   // B1: lg_s complete; staged p^1 complete
        // bookkeeping: EACH compute wave's lanes 0-11 redundantly update
        // private (ms,ss) and write this wave's w_s/sc_s slice.
        if (t < 192 && lane < 12) {
            float l0 = lg_s[0 * 16 + lane], l1 = lg_s[1 * 16 + lane];
            float l2 = lg_s[2 * 16 + lane], l3 = lg_s[3 * 16 + lane];
            float mt = fmaxf(fmaxf(l0, l1), fmaxf(l2, l3));
            float mn = fmaxf(ms, mt);
            float sc = __expf(ms - mn);
            float e0 = __expf(l0 - mn), e1 = __expf(l1 - mn);
            float e2 = __expf(l2 - mn), e3 = __expf(l3 - mn);
            w_s[w * 64 + 0 * 16 + lane] = e0; w_s[w * 64 + 1 * 16 + lane] = e1;
            w_s[w * 64 + 2 * 16 + lane] = e2; w_s[w * 64 + 3 * 16 + lane] = e3;
            sc_s[w * 16 + lane] = sc;
            ms = mn;
            ss = ss * sc + (e0 + e1 + e2 + e3);
        }
        // phase2: t<192 owns 4 contiguous d-cols; reads OWN wave's w_s/sc_s
        // (in-wave write->read ordering via lgkmcnt, no barrier).
        if (t < 192) {
            const float* xb = &xs[p * 4 * XP];
            const float4* w4 = (const float4*)&w_s[w * 64];
            const float4* sc4 = (const float4*)&sc_s[w * 16];
            float4 sa = sc4[0], sb = sc4[1], sc = sc4[2];
            acc4[0].x *= sa.x; acc4[0].y *= sa.x; acc4[0].z *= sa.x; acc4[0].w *= sa.x;
            acc4[1].x *= sa.y; acc4[1].y *= sa.y; acc4[1].z *= sa.y; acc4[1].w *= sa.y;
            acc4[2].x *= sa.z; acc4[2].y *= sa.z; acc4[2].z *= sa.z; acc4[2].w *= sa.z;
            acc4[3].x *= sa.w; acc4[3].y *= sa.w; acc4[3].z *= sa.w; acc4[3].w *= sa.w;
            acc4[4].x *= sb.x; acc4[4].y *= sb.x; acc4[4].z *= sb.x; acc4[4].w *= sb.x;
            acc4[5].x *= sb.y; acc4[5].y *= sb.y; acc4[5].z *= sb.y; acc4[5].w *= sb.y;
            acc4[6].x *= sb.z; acc4[6].y *= sb.z; acc4[6].z *= sb.z; acc4[6].w *= sb.z;
            acc4[7].x *= sb.w; acc4[7].y *= sb.w; acc4[7].z *= sb.w; acc4[7].w *= sb.w;
            acc4[8].x *= sc.x; acc4[8].y *= sc.x; acc4[8].z *= sc.x; acc4[8].w *= sc.x;
            acc4[9].x *= sc.y; acc4[9].y *= sc.y; acc4[9].z *= sc.y; acc4[9].w *= sc.y;
            acc4[10].x *= sc.z; acc4[10].y *= sc.z; acc4[10].z *= sc.z; acc4[10].w *= sc.z;
            acc4[11].x *= sc.w; acc4[11].y *= sc.w; acc4[11].z *= sc.w; acc4[11].w *= sc.w;
            #pragma unroll
            for (int l = 0; l < 4; ++l) {
                float4 xv = *(const float4*)&xb[l * XP + 4 * t];
                float4 wa = w4[l * 4], wb = w4[l * 4 + 1], wc = w4[l * 4 + 2];
                acc4[0].x += wa.x * xv.x; acc4[0].y += wa.x * xv.y; acc4[0].z += wa.x * xv.z; acc4[0].w += wa.x * xv.w;
                acc4[1].x += wa.y * xv.x; acc4[1].y += wa.y * xv.y; acc4[1].z += wa.y * xv.z; acc4[1].w += wa.y * xv.w;
                acc4[2].x += wa.z * xv.x; acc4[2].y += wa.z * xv.y; acc4[2].z += wa.z * xv.z; acc4[2].w += wa.z * xv.w;
                acc4[3].x += wa.w * xv.x; acc4[3].y += wa.w * xv.y; acc4[3].z += wa.w * xv.z; acc4[3].w += wa.w * xv.w;
                acc4[4].x += wb.x * xv.x; acc4[4].y += wb.x * xv.y; acc4[4].z += wb.x * xv.z; acc4[4].w += wb.x * xv.w;
                acc4[5].x += wb.y * xv.x; acc4[5].y += wb.y * xv.y; acc4[5].z += wb.y * xv.z; acc4[5].w += wb.y * xv.w;
                acc4[6].x += wb.z * xv.x; acc4[6].y += wb.z * xv.y; acc4[6].z += wb.z * xv.z; acc4[6].w += wb.z * xv.w;
                acc4[7].x += wb.w * xv.x; acc4[7].y += wb.w * xv.y; acc4[7].z += wb.w * xv.z; acc4[7].w += wb.w * xv.w;
                acc4[8].x += wc.x * xv.x; acc4[8].y += wc.x * xv.y; acc4[8].z += wc.x * xv.z; acc4[8].w += wc.x * xv.w;
                acc4[9].x += wc.y * xv.x; acc4[9].y += wc.y * xv.y; acc4[9].z += wc.y * xv.z; acc4[9].w += wc.y * xv.w;
                acc4[10].x += wc.z * xv.x; acc4[10].y += wc.z * xv.y; acc4[10].z += wc.z * xv.z; acc4[10].w += wc.z * xv.w;
                acc4[11].x += wc.w * xv.x; acc4[11].y += wc.w * xv.y; acc4[11].z += wc.w * xv.z; acc4[11].w += wc.w * xv.w;
            }
        }
        __syncthreads();   // B2: reads of buf p done; next iter may overwrite
        p ^= 1;
    }
    // write partials + per-chunk stats. xbp layout [lc][h][n][d].
    if (t < 192) {
        #pragma unroll
        for (int h = 0; h < 12; ++h)
            *(float4*)&xbp[(((size_t)lc * 12 + h) * 32 + n) * 768 + 4 * t] = acc4[h];
    }
    if (w == 0 && lane < 12) {
        mlc[((size_t)n * 12 + lane) * 32 + lc] = ms;
        slc[((size_t)n * 12 + lane) * 32 + lc] = ss;
    }
}

// ---------------------------------------------------------------------------
// o partials: op[kk][n][h*64+e] = sum_{d in kk} xbar[n,h,d]*wv[d,h,e] (+bv@kk0).
// Grid (12 h, 8 kk, 4 ng): ng handles 8 n -> 384 blocks (was 96; tail kernels
// are latency-bound at <1 block/CU). Gather d-fastest coalesced; xb_s pitch 9.
__global__ __launch_bounds__(256) void oproj_kernel(
    const float* __restrict__ xbp, const float* __restrict__ mlc,
    const float* __restrict__ slc, const float* __restrict__ wv,
    const float* __restrict__ bv, float* __restrict__ op) {
    int h = blockIdx.x, kk = blockIdx.y, ng8 = blockIdx.z, t = threadIdx.x;
    int d0 = kk * 96, n0 = ng8 * 8;
    __shared__ __align__(16) float wv_s[96 * 64];
    __shared__ __align__(16) float xb_s[96 * 9];
    __shared__ float scl_s[32 * 8];    // [lc][nn_local]
    if (t < 8) {
        int n = n0 + t;
        float M = -1e30f;
        #pragma unroll
        for (int c = 0; c < 32; ++c) M = fmaxf(M, mlc[((size_t)n * 12 + h) * 32 + c]);
        float T = 0.f;
        float e[32];
        #pragma unroll
        for (int c = 0; c < 32; ++c) {
            e[c] = __expf(mlc[((size_t)n * 12 + h) * 32 + c] - M);
            T += slc[((size_t)n * 12 + h) * 32 + c] * e[c];
        }
        float inv = 1.f / T;
        #pragma unroll
        for (int c = 0; c < 32; ++c) scl_s[c * 8 + t] = e[c] * inv;
    }
    for (int i = t; i < 96 * 64; i += 256) {
        int d = i >> 6, e = i & 63;
        wv_s[i] = wv[(size_t)(d0 + d) * 768 + h * 64 + e];
    }
    __syncthreads();
    for (int idx = t; idx < 96 * 8; idx += 256) {
        int d = idx % 96, nn = idx / 96;   // consecutive lanes -> consecutive d
        float s = 0.f;
        #pragma unroll
        for (int lcc = 0; lcc < 32; ++lcc)
            s += xbp[(((size_t)lcc * 12 + h) * 32 + (n0 + nn)) * 768 + d0 + d]
               * scl_s[lcc * 8 + nn];
        xb_s[d * 9 + nn] = s;
    }
    __syncthreads();
    int e = t & 63, ngg = t >> 6;          // 4 wave-groups x 2 n each
    float acc0 = 0.f, acc1 = 0.f;
    for (int d = 0; d < 96; ++d) {
        float wvv = wv_s[d * 64 + e];
        acc0 += xb_s[d * 9 + ngg * 2 + 0] * wvv;
        acc1 += xb_s[d * 9 + ngg * 2 + 1] * wvv;
    }
    float bvv = (kk == 0) ? bv[h * 64 + e] : 0.f;
    op[(size_t)kk * 24576 + (size_t)(n0 + ngg * 2 + 0) * 768 + h * 64 + e] = acc0 + bvv;
    op[(size_t)kk * 24576 + (size_t)(n0 + ngg * 2 + 1) * 768 + h * 64 + e] = acc1 + bvv;
}

// xa partials: xap[kk][n][d] = sum_{i in kk} o[n][i]*wo[i*768+d] (+bo@kk0).
// Grid (3 dtile, 8 kk). o summed from its 8 partials; gather i-fastest
// (coalesced), o_s pitch 36.
__global__ __launch_bounds__(256) void xaproj_kernel(
    const float* __restrict__ op, const float* __restrict__ wo,
    const float* __restrict__ bo, float* __restrict__ xap) {
    int dt = blockIdx.x, kk = blockIdx.y, t = threadIdx.x;
    int i0 = kk * 96;
    __shared__ __align__(16) float o_s[96 * 36];
    for (int idx = t; idx < 96 * 32; idx += 256) {
        int i = idx % 96, nn = idx / 96;   // consecutive lanes -> consecutive i
        float s = 0.f;
        #pragma unroll
        for (int pp = 0; pp < 8; ++pp)
            s += op[(size_t)pp * 24576 + (size_t)nn * 768 + i0 + i];
        o_s[i * 36 + nn] = s;
    }
    __syncthreads();
    int d = dt * 256 + t;
    float acc[32];
    #pragma unroll
    for (int nn = 0; nn < 32; ++nn) acc[nn] = 0.f;
    for (int i = 0; i < 96; ++i) {
        float w = wo[(size_t)(i0 + i) * 768 + d];
        const float4* o4 = (const float4*)&o_s[i * 36];
        #pragma unroll
        for (int qq = 0; qq < 8; ++qq) {
            float4 f = o4[qq];
            acc[qq * 4 + 0] += f.x * w; acc[qq * 4 + 1] += f.y * w;
            acc[qq * 4 + 2] += f.z * w; acc[qq * 4 + 3] += f.w * w;
        }
    }
    float bov = (kk == 0) ? bo[d] : 0.f;
    #pragma unroll
    for (int nn = 0; nn < 32; ++nn)
        xap[(size_t)kk * 24576 + (size_t)nn * 768 + d] = acc[nn] + bov;
}

// ---------------------------------------------------------------------------
// xa = sum of 8 partials (stored to xas for the residual); y = LayerNorm(xa).
__global__ __launch_bounds__(256) void ln_kernel(
    const float* __restrict__ xap, const float* __restrict__ ln_scale,
    const float* __restrict__ ln_bias, float* __restrict__ xas,
    float* __restrict__ y) {
    int n = blockIdx.x, tid = threadIdx.x;
    __shared__ float xs[768];
    __shared__ float red[4];
    for (int i = tid; i < 768; i += 256) {
        float s = 0.f;
        #pragma unroll
        for (int pp = 0; pp < 8; ++pp)
            s += xap[(size_t)pp * 24576 + (size_t)n * 768 + i];
        xs[i] = s;
        xas[(size_t)n * 768 + i] = s;
    }
    __syncthreads();
    float lsum = 0.f;
    for (int i = tid; i < 768; i += 256) lsum += xs[i];
    #pragma unroll
    for (int off = 32; off > 0; off >>= 1) lsum += __shfl_xor(lsum, off);
    int wave = tid >> 6;
    if ((tid & 63) == 0) red[wave] = lsum;
    __syncthreads();
    float mu = (red[0] + red[1] + red[2] + red[3]) * (1.f / 768.f);
    __syncthreads();
    float lsq = 0.f;
    for (int i = tid; i < 768; i += 256) { float c = xs[i] - mu; lsq += c * c; }
    #pragma unroll
    for (int off = 32; off > 0; off >>= 1) lsq += __shfl_xor(lsq, off);
    if ((tid & 63) == 0) red[wave] = lsq;
    __syncthreads();
    float var = (red[0] + red[1] + red[2] + red[3]) * (1.f / 768.f);
    float rs = rsqrtf(var + 1e-6f);
    for (int i = tid; i < 768; i += 256)
        y[(size_t)n * 768 + i] = (xs[i] - mu) * rs * ln_scale[i] + ln_bias[i];
}

// ---------------------------------------------------------------------------
// h1 partials: h1p[kk][j][nn] (j-major) = sum_{d in kk(48)} y[n][d]*w1[d][j].
// Grid (12 jtile, 16 kk). Store is per-thread-contiguous (float4).
__global__ __launch_bounds__(256) void mlp1_kernel(
    const float* __restrict__ y, const float* __restrict__ w1,
    float* __restrict__ h1p) {
    int jt = blockIdx.x, kk = blockIdx.y, t = threadIdx.x;
    int d0 = kk * 48;
    __shared__ __align__(16) float y_s[48 * 32];
    for (int idx = t; idx < 48 * 32; idx += 256) {
        int d = idx >> 5, nn = idx & 31;
        y_s[idx] = y[(size_t)nn * 768 + d0 + d];
    }
    __syncthreads();
    int j = jt * 256 + t;
    float acc[32];
    #pragma unroll
    for (int nn = 0; nn < 32; ++nn) acc[nn] = 0.f;
    for (int d = 0; d < 48; ++d) {
        float w = w1[(size_t)(d0 + d) * 3072 + j];
        const float4* y4 = (const float4*)&y_s[d * 32];
        #pragma unroll
        for (int qq = 0; qq < 8; ++qq) {
            float4 f = y4[qq];
            acc[qq * 4 + 0] += f.x * w; acc[qq * 4 + 1] += f.y * w;
            acc[qq * 4 + 2] += f.z * w; acc[qq * 4 + 3] += f.w * w;
        }
    }
    float* dst = h1p + (size_t)kk * 98304 + (size_t)j * 32;
    #pragma unroll
    for (int qq = 0; qq < 8; ++qq)
        *(float4*)&dst[qq * 4] = make_float4(acc[qq * 4], acc[qq * 4 + 1],
                                             acc[qq * 4 + 2], acc[qq * 4 + 3]);
}

// macc partials: maccp[kk][n][d] = sum_{j in kk(48)} gelu(h1+b1)[n][j]*w2[j][d].
// Grid (3 dtile, 64 kk). h1 gather linear in idx (h1p j-major) -> coalesced.
__global__ __launch_bounds__(256) void mlp2_kernel(
    const float* __restrict__ h1p, const float* __restrict__ b1,
    const float* __restrict__ w2, float* __restrict__ maccp) {
    int dt = blockIdx.x, kk = blockIdx.y, t = threadIdx.x;
    int j0 = kk * 48;
    __shared__ __align__(16) float h_s[48 * 32];
    for (int idx = t; idx < 48 * 32; idx += 256) {
        int j = idx >> 5;
        float tv = b1[j0 + j];
        #pragma unroll
        for (int pp = 0; pp < 16; ++pp)
            tv += h1p[(size_t)pp * 98304 + (size_t)j0 * 32 + idx];
        float u = 0.7978845608028654f * (tv + 0.044715f * tv * tv * tv);
        h_s[idx] = 0.5f * tv * (1.f + tanhf(u));
    }
    __syncthreads();
    int d = dt * 256 + t;
    float acc[32];
    #pragma unroll
    for (int nn = 0; nn < 32; ++nn) acc[nn] = 0.f;
    for (int j = 0; j < 48; ++j) {
        float w = w2[(size_t)(j0 + j) * 768 + d];
        const float4* h4 = (const float4*)&h_s[j * 32];
        #pragma unroll
        for (int qq = 0; qq < 8; ++qq) {
            float4 f = h4[qq];
            acc[qq * 4 + 0] += f.x * w; acc[qq * 4 + 1] += f.y * w;
            acc[qq * 4 + 2] += f.z * w; acc[qq * 4 + 3] += f.w * w;
        }
    }
    #pragma unroll
    for (int nn = 0; nn < 32; ++nn)
        maccp[(size_t)kk * 24576 + (size_t)nn * 768 + d] = acc[nn];
}

// out = xas + b2 + sum_64 maccp. Grid (32 n, 3 dt) for latency parallelism.
__global__ __launch_bounds__(256) void final_kernel(
    const float* __restrict__ xas, const float* __restrict__ b2,
    const float* __restrict__ maccp, float* __restrict__ out) {
    int n = blockIdx.x, dt = blockIdx.y, t = threadIdx.x;
    int i = dt * 256 + t;
    float s = xas[(size_t)n * 768 + i] + b2[i];
    #pragma unroll
    for (int k = 0; k < 64; ++k)
        s += maccp[(size_t)k * 24576 + (size_t)n * 768 + i];
    out[(size_t)n * 768 + i] = s;
}

// ---------------------------------------------------------------------------
extern "C" void kernel_launch(void* const* d_in, const int* in_sizes, int n_in,
                              void* d_out, int out_size, void* d_ws, size_t ws_size,
                              hipStream_t stream) {
    const float* x        = (const float*)d_in[0];
    const float* probe    = (const float*)d_in[1];
    const float* wq       = (const float*)d_in[2];
    const float* bq       = (const float*)d_in[3];
    const float* wk       = (const float*)d_in[4];
    const float* bk       = (const float*)d_in[5];
    const float* wv       = (const float*)d_in[6];
    const float* bv       = (const float*)d_in[7];
    const float* wo       = (const float*)d_in[8];
    const float* bo       = (const float*)d_in[9];
    const float* ln_scale = (const float*)d_in[10];
    const float* ln_bias  = (const float*)d_in[11];
    const float* w1       = (const float*)d_in[12];
    const float* b1       = (const float*)d_in[13];
    const float* w2       = (const float*)d_in[14];
    const float* b2       = (const float*)d_in[15];
    float* out = (float*)d_out;
    float* ws  = (float*)d_ws;

    float* qhp   = ws + WS_QHP;
    float* qk    = ws + WS_QK;
    float* qb    = ws + WS_QB;
    float* mlc   = ws + WS_MLC;
    float* slc   = ws + WS_SLC;
    float* xbp   = ws + WS_XBP;
    float* op    = ws + WS_OP;
    float* xap   = ws + WS_XAP;
    float* xas   = ws + WS_XAS;
    float* y     = ws + WS_Y;
    float* h1p   = ws + WS_H1P;
    float* maccp = ws + WS_MACCP;

    qh_kernel<<<dim3(3, 16), 256, 0, stream>>>(probe, wq, bq, qhp);
    qk_kernel<<<dim3(12, 3), 256, 0, stream>>>(qhp, wk, bk, qk, qb);
    attn_fused<<<dim3(NCH, 32), 256, 0, stream>>>(x, qk, qb, xbp, mlc, slc);
    oproj_kernel<<<dim3(12, 8, 4), 256, 0, stream>>>(xbp, mlc, slc, wv, bv, op);
    xaproj_kernel<<<dim3(3, 8), 256, 0, stream>>>(op, wo, bo, xap);
    ln_kernel<<<N_B, 256, 0, stream>>>(xap, ln_scale, ln_bias, xas, y);
    mlp1_kernel<<<dim3(12, 16), 256, 0, stream>>>(y, w1, h1p);
    mlp2_kernel<<<dim3(3, 64), 256, 0, stream>>>(h1p, b1, w2, maccp);
    final_kernel<<<dim3(N_B, 3), 256, 0, stream>>>(xas, b2, maccp, out);
}